// Round 7
// baseline (392.142 us; speedup 1.0000x reference)
//
#include <hip/hip_runtime.h>
#include <math.h>

// L=1024 B=2 F=1024 E=2 H=2048 N=16 R=64 K=4, M=2048 rows (m = l*2+b).
// Round-7: scan loads diet — dt/u rows staged in LDS, proj stored with B/C
// interleaved (B_n at col 2n, C_n at 2n+1, dtraw at 64..127) so pass2 is one
// float2 per (token,n). GEMM core (global_load_lds + XOR swizzle) unchanged.
//   T : WT_in, WT_conv, WT_out, WT_ssm, WT_dt (bf16 [n][k]); xb = bf16(x)
//   G1: h = xb @ WT_in^T -> xs(bf16 [m][ch] via LDS repack) | resT(bf16 [h][m])
//   C : conv gather-GEMM -> u_mh(repack) + uT direct, +bias, silu
//   G3: proj = u @ W_ssm, split-K=4, fp32 atomics, interleaved cols
//   G4: deltaT = clip(softplus(dtraw @ W_dt + b_dt))^T  (fp32 [h][m])
//   S : scan, 1 block/h, 2 states/lane, LDS-staged rows -> zT bf16 [h][m]
//   TZ: zT -> z_mh (bf16 transpose)
//   G5: out = z_mh @ WT_out^T (fp32)

typedef unsigned short u16;
typedef unsigned int u32;
typedef __attribute__((ext_vector_type(8))) short short8;
typedef __attribute__((ext_vector_type(4))) float floatx4;
typedef __attribute__((ext_vector_type(4))) u16 ushort4v;

__device__ __forceinline__ u16 f2bf(float f) {
    u32 u = __float_as_uint(f);
    return (u16)((u + 0x7fffu + ((u >> 16) & 1u)) >> 16);
}
__device__ __forceinline__ float bf2f(u16 v) {
    return __uint_as_float((u32)v << 16);
}

// async global->LDS, 16 bytes per lane
__device__ __forceinline__ void gl_lds16(const u16* g, u16* l) {
    auto gp = reinterpret_cast<const __attribute__((address_space(1))) u32*>(
        reinterpret_cast<uintptr_t>(g));
    auto lp = reinterpret_cast<__attribute__((address_space(3))) u32*>(
        reinterpret_cast<uintptr_t>(l));
    __builtin_amdgcn_global_load_lds(gp, lp, 16, 0, 0);
}

// ---------------- fp32 -> bf16 transpose:  S[R][C] -> D[C][R], vec writes ----------
__global__ __launch_bounds__(256) void trans_k(const float* __restrict__ S,
                                               u16* __restrict__ D, int R, int C)
{
    __shared__ u16 t[64][65];
    int br = blockIdx.x * 64;
    int bc = blockIdx.y * 64;
    int c = threadIdx.x & 63;
    int r0 = threadIdx.x >> 6;
#pragma unroll
    for (int i = 0; i < 16; ++i) {
        int r = r0 + i * 4;
        float v = 0.f;
        if (br + r < R && bc + c < C) v = S[(size_t)(br + r) * C + bc + c];
        t[r][c] = f2bf(v);
    }
    __syncthreads();
    int cc0 = threadIdx.x >> 4;          // 0..15
    int rr0 = (threadIdx.x & 15) * 4;    // R is always a multiple of 64 here
#pragma unroll
    for (int i = 0; i < 4; ++i) {
        int cc = i * 16 + cc0;
        if (bc + cc < C) {
            ushort4v o;
#pragma unroll
            for (int k = 0; k < 4; ++k) o[k] = t[rr0 + k][cc];
            *(ushort4v*)(D + (size_t)(bc + cc) * R + br + rr0) = o;
        }
    }
}

// ---------------- bf16 [2048][2048] transpose (zT -> z_mh) ----------------
__global__ __launch_bounds__(256) void tbf_k(const u16* __restrict__ S,
                                             u16* __restrict__ D)
{
    __shared__ u16 t[64][68];
    int br = blockIdx.x * 64;
    int bc = blockIdx.y * 64;
    int c = threadIdx.x & 63;
    int r0 = threadIdx.x >> 6;
#pragma unroll
    for (int i = 0; i < 16; ++i) {
        int r = r0 + i * 4;
        t[r][c] = S[(size_t)(br + r) * 2048 + bc + c];
    }
    __syncthreads();
#pragma unroll
    for (int i = 0; i < 16; ++i) {
        int r = r0 + i * 4;
        D[(size_t)(bc + r) * 2048 + br + c] = t[c][r];
    }
}

// ---------------- x fp32 -> bf16 ----------------
__global__ __launch_bounds__(256) void cvt_k(const float* __restrict__ S, u16* __restrict__ D)
{
    int i = (blockIdx.x * 256 + threadIdx.x) * 4;
    float4 v = *(const float4*)(S + i);
    u16 o[4] = {f2bf(v.x), f2bf(v.y), f2bf(v.z), f2bf(v.w)};
    *(ulong1*)(D + i) = *(ulong1*)o;
}

// ---------------- proj dt-columns (64..127) fp32 -> bf16 [2048][64] ----------------
__global__ __launch_bounds__(256) void cvtdt_k(const float* __restrict__ proj,
                                               u16* __restrict__ pb)
{
    int g = blockIdx.x * 256 + threadIdx.x;
    int m = g >> 4, i = (g & 15) * 4;
    float4 v = *(const float4*)(proj + (size_t)m * 128 + 64 + i);
    u16 o[4] = {f2bf(v.x), f2bf(v.y), f2bf(v.z), f2bf(v.w)};
    *(ulong1*)(pb + (size_t)m * 64 + i) = *(ulong1*)o;
}

// ================= m97-style GEMM: A[M][K] x B[N][K]^T, tile 128x64, BK=64 =========
// MODE 0: G1 split — bn<2048: xs[m][h] via LDS repack; else resT[h][m] direct
// MODE 1: conv gather (+zero-fix), +bias+silu -> u_mh (repack) + uT direct
// MODE 2: plain fp32 [m][n]
template<int MODE>
__global__ __launch_bounds__(256) void gls_k(
    const u16* __restrict__ A, int lda,
    const u16* __restrict__ B, int ldb,
    float* __restrict__ Cf, int ldc,
    u16* __restrict__ Cb0, u16* __restrict__ Cb1,
    const float* __restrict__ bias, int nkt)
{
    __shared__ u16 As[128 * 64];
    __shared__ u16 Bs[64 * 64];
    const int tid = threadIdx.x;
    const int bm = blockIdx.y * 128;
    const int bn = blockIdx.x * 64;
    const int gofs = (MODE == 1 && bn >= 1024) ? 1024 : 0;
    const int lane = tid & 63, wave = tid >> 6, wm = wave * 32;
    const int m16 = lane & 15, q = lane >> 4;
    floatx4 acc[2][4] = {};

    const int rsub = lane >> 3;
    const int pch  = lane & 7;

    for (int kt = 0; kt < nkt; ++kt) {
        const int k0 = kt * 64;
        int tap = 0, ck = k0;
        if (MODE == 1) { tap = k0 >> 10; ck = k0 & 1023; }
#pragma unroll
        for (int i = 0; i < 4; ++i) {
            int r = i * 32 + wave * 8 + rsub;
            int c = pch ^ (r & 7);
            const u16* g;
            if (MODE == 1) {
                int rg = bm + r + 2 * tap - 6;
                g = A + (size_t)rg * lda + gofs + ck + c * 8;
            } else {
                g = A + (size_t)(bm + r) * lda + k0 + c * 8;
            }
            gl_lds16(g, As + i * 2048 + wave * 512);
        }
#pragma unroll
        for (int i = 0; i < 2; ++i) {
            int r = i * 32 + wave * 8 + rsub;
            int c = pch ^ (r & 7);
            gl_lds16(B + (size_t)(bn + r) * ldb + k0 + c * 8,
                     Bs + i * 2048 + wave * 512);
        }
        if (MODE == 1 && bm == 0) {
            int zr = 6 - 2 * tap;
            if (zr > 0) {
                asm volatile("s_waitcnt vmcnt(0)" ::: "memory");
                if (tid < 64) {
                    int r = tid >> 3;
                    if (r < zr) *(short8*)(As + r * 64 + (tid & 7) * 8) = short8{};
                }
            }
        }
        __syncthreads();

#pragma unroll
        for (int ks = 0; ks < 2; ++ks) {
            short8 af[2], bfr[4];
#pragma unroll
            for (int ti = 0; ti < 2; ++ti) {
                int r = wm + ti * 16 + m16;
                int p = (ks * 4 + q) ^ (r & 7);
                af[ti] = *(const short8*)(As + r * 64 + p * 8);
            }
#pragma unroll
            for (int tj = 0; tj < 4; ++tj) {
                int r = tj * 16 + m16;
                int p = (ks * 4 + q) ^ (r & 7);
                bfr[tj] = *(const short8*)(Bs + r * 64 + p * 8);
            }
#pragma unroll
            for (int ti = 0; ti < 2; ++ti)
#pragma unroll
                for (int tj = 0; tj < 4; ++tj)
                    acc[ti][tj] = __builtin_amdgcn_mfma_f32_16x16x32_bf16(
                        af[ti], bfr[tj], acc[ti][tj], 0, 0, 0);
        }
        __syncthreads();
    }

    if (MODE == 2) {
#pragma unroll
        for (int tj = 0; tj < 4; ++tj) {
            int gn = bn + tj * 16 + m16;
#pragma unroll
            for (int ti = 0; ti < 2; ++ti) {
                int gm0 = bm + wm + ti * 16 + q * 4;
#pragma unroll
                for (int r = 0; r < 4; ++r)
                    Cf[(size_t)(gm0 + r) * ldc + gn] = acc[ti][tj][r];
            }
        }
        return;
    }
    if (MODE == 0 && bn >= 2048) {
#pragma unroll
        for (int tj = 0; tj < 4; ++tj) {
            int gn = bn + tj * 16 + m16;
#pragma unroll
            for (int ti = 0; ti < 2; ++ti) {
                int gm0 = bm + wm + ti * 16 + q * 4;
                ushort4v h;
#pragma unroll
                for (int r = 0; r < 4; ++r) h[r] = f2bf(acc[ti][tj][r]);
                *(ushort4v*)(Cb1 + (size_t)(gn - 2048) * 2048 + gm0) = h;
            }
        }
        return;
    }
#pragma unroll
    for (int tj = 0; tj < 4; ++tj) {
        int gn = bn + tj * 16 + m16;
        float bv = (MODE == 1) ? bias[gn] : 0.f;
#pragma unroll
        for (int ti = 0; ti < 2; ++ti) {
            int lr0 = wm + ti * 16 + q * 4;
            ushort4v h;
#pragma unroll
            for (int r = 0; r < 4; ++r) {
                float v = acc[ti][tj][r];
                if (MODE == 1) {
                    v += bv;
                    v = v / (1.f + __expf(-v));
                }
                u16 hv = f2bf(v);
                h[r] = hv;
                As[(lr0 + r) * 64 + tj * 16 + m16] = hv;
            }
            if (MODE == 1)
                *(ushort4v*)(Cb1 + (size_t)gn * 2048 + bm + lr0) = h;
        }
    }
    __syncthreads();
    {
        int row = tid >> 1, half = tid & 1;
        u16* gdst = Cb0 + (size_t)(bm + row) * 2048 + bn + half * 32;
        const u16* lsrc = As + row * 64 + half * 32;
#pragma unroll
        for (int i = 0; i < 4; ++i)
            *(short8*)(gdst + i * 8) = *(const short8*)(lsrc + i * 8);
    }
}

// ---------------- G3: proj = u @ W_ssm, split-K MFMA, interleaved atomics ----------
#define APAD 40
__global__ __launch_bounds__(256) void g3_k(
    const u16* __restrict__ A,      // u_mh bf16 [2048][2048]
    const u16* __restrict__ Bw,     // WT_ssm bf16 [128][2048] (rows 96+ junk)
    float* __restrict__ proj)       // [2048][128] fp32, pre-zeroed
{
    __shared__ u16 As[128 * APAD];
    __shared__ u16 Bs[64 * APAD];
    const int tid = threadIdx.x;
    const int bn = blockIdx.x * 64;
    const int bm = blockIdx.y * 128;
    const int kb = blockIdx.z * 512;
    const int lane = tid & 63, wave = tid >> 6, wm = wave * 32;
    const int m16 = lane & 15, q = lane >> 4;
    floatx4 acc[2][4] = {};
    const int ar = tid >> 2, ac = (tid & 3) * 8;

    for (int kt = 0; kt < 16; ++kt) {
        const int k0 = kb + kt * 32;
#pragma unroll
        for (int p = 0; p < 2; ++p) {
            int r = ar + p * 64;
            *(short8*)(As + r * APAD + ac) =
                *(const short8*)(A + (size_t)(bm + r) * 2048 + k0 + ac);
        }
        *(short8*)(Bs + ar * APAD + ac) =
            *(const short8*)(Bw + (size_t)(bn + ar) * 2048 + k0 + ac);
        __syncthreads();

        short8 af[2], bfr[4];
#pragma unroll
        for (int ti = 0; ti < 2; ++ti)
            af[ti] = *(const short8*)(As + (wm + ti * 16 + m16) * APAD + q * 8);
#pragma unroll
        for (int tj = 0; tj < 4; ++tj)
            bfr[tj] = *(const short8*)(Bs + (tj * 16 + m16) * APAD + q * 8);
#pragma unroll
        for (int ti = 0; ti < 2; ++ti)
#pragma unroll
            for (int tj = 0; tj < 4; ++tj)
                acc[ti][tj] = __builtin_amdgcn_mfma_f32_16x16x32_bf16(
                    af[ti], bfr[tj], acc[ti][tj], 0, 0, 0);
        __syncthreads();
    }

    // interleaved col map: B_n->2n, C_n->2n+1, dtraw_r->64+r; junk (gn>=96) dropped
#pragma unroll
    for (int tj = 0; tj < 4; ++tj) {
        int gn = bn + tj * 16 + m16;
        if (gn >= 96) continue;
        int col = (gn < 16) ? (2 * gn) : (gn < 32 ? 2 * (gn - 16) + 1 : 32 + gn);
#pragma unroll
        for (int ti = 0; ti < 2; ++ti)
#pragma unroll
            for (int r = 0; r < 4; ++r) {
                int gm = bm + wm + ti * 16 + q * 4 + r;
                atomicAdd(proj + (size_t)gm * 128 + col, acc[ti][tj][r]);
            }
    }
}

// ---------------- G4: deltaT = clip(softplus(dtraw @ W_dt + b_dt))^T (K=64) --------
__global__ __launch_bounds__(256) void g4_k(
    const u16* __restrict__ A,      // pb_dt bf16 [2048][64]
    const u16* __restrict__ B,      // WT_dt bf16 [2048][64]
    const float* __restrict__ bias,
    float* __restrict__ Cf)         // deltaT fp32 [h][m], ld 2048
{
    __shared__ u16 As[128 * APAD];
    __shared__ u16 Bs[64 * APAD];
    const int tid = threadIdx.x;
    const int bm = blockIdx.y * 128;
    const int bn = blockIdx.x * 64;
    const int lane = tid & 63, wave = tid >> 6, wm = wave * 32;
    const int m16 = lane & 15, q = lane >> 4;
    floatx4 acc[2][4] = {};
    const int ar = tid >> 2, ac = (tid & 3) * 8;

    for (int kt = 0; kt < 2; ++kt) {
        const int k0 = kt * 32;
#pragma unroll
        for (int p = 0; p < 2; ++p) {
            int r = ar + p * 64;
            *(short8*)(As + r * APAD + ac) =
                *(const short8*)(A + (size_t)(bm + r) * 64 + k0 + ac);
        }
        *(short8*)(Bs + ar * APAD + ac) =
            *(const short8*)(B + (size_t)(bn + ar) * 64 + k0 + ac);
        __syncthreads();
        short8 af[2], bfr[4];
#pragma unroll
        for (int ti = 0; ti < 2; ++ti)
            af[ti] = *(const short8*)(As + (wm + ti * 16 + m16) * APAD + q * 8);
#pragma unroll
        for (int tj = 0; tj < 4; ++tj)
            bfr[tj] = *(const short8*)(Bs + (tj * 16 + m16) * APAD + q * 8);
#pragma unroll
        for (int ti = 0; ti < 2; ++ti)
#pragma unroll
            for (int tj = 0; tj < 4; ++tj)
                acc[ti][tj] = __builtin_amdgcn_mfma_f32_16x16x32_bf16(
                    af[ti], bfr[tj], acc[ti][tj], 0, 0, 0);
        __syncthreads();
    }
#pragma unroll
    for (int tj = 0; tj < 4; ++tj) {
        int gn = bn + tj * 16 + m16;
        float bv = bias[gn];
#pragma unroll
        for (int ti = 0; ti < 2; ++ti) {
            int gm0 = bm + wm + ti * 16 + q * 4;
            float t[4];
#pragma unroll
            for (int r = 0; r < 4; ++r) {
                float v = acc[ti][tj][r] + bv;
                v = (v > 15.f) ? v : log1pf(__expf(v));
                t[r] = fminf(fmaxf(v, 0.001f), 0.1f);
            }
            *(float4*)(Cf + (size_t)gn * 2048 + gm0) =
                make_float4(t[0], t[1], t[2], t[3]);
        }
    }
}

// ---------------- scan: 1 block/h, LDS-staged rows, interleaved BC ----------------
__global__ __launch_bounds__(512) void scan5_k(
    const float* __restrict__ deltaT,  // [2048 h][2048 m]
    const u16* __restrict__ uT,        // [2048 h][2048 m] bf16
    const float* __restrict__ proj,    // [2048 m][128] interleaved (BC|..|dt)
    const float* __restrict__ A_log,
    const float* __restrict__ Dvec,
    const u16* __restrict__ resT,      // [2048 h][2048 m] bf16
    u16* __restrict__ zT)              // [2048 h][2048 m] bf16
{
    __shared__ float lP[2][32][16], lS[2][32][16], lI[2][32][16];
    __shared__ float yrow[2048];
    __shared__ float sdt[2048];
    __shared__ u16   su[2048];
    const int h = blockIdx.x;
    const int tid = threadIdx.x;
    const int n = tid & 15;
    const int c = tid >> 4;
    const int l0 = c * 32;

    const float Ahn = -__expf(A_log[h * 16 + n]);

    // stage dt + u rows (coalesced, once)
    {
        int t4 = tid * 4;
        *(float4*)(sdt + t4) = *(const float4*)(deltaT + (size_t)h * 2048 + t4);
        *(ushort4v*)(su + t4) = *(const ushort4v*)(uT + (size_t)h * 2048 + t4);
    }
    __syncthreads();

    float s0 = 0.f, s1 = 0.f, T0 = 0.f, T1 = 0.f;
    for (int j = 0; j < 32; ++j) {
        int l = l0 + j;
        float2 dtv = *(const float2*)(sdt + 2 * l);
        u32 uv = *(const u32*)(su + 2 * l);
        float uu0 = __uint_as_float(uv << 16);
        float uu1 = __uint_as_float(uv & 0xffff0000u);
        float B0 = proj[(size_t)(2 * l) * 128 + 2 * n];
        float B1 = proj[(size_t)(2 * l + 1) * 128 + 2 * n];
        float e0 = __expf(dtv.x * Ahn);
        float e1 = __expf(dtv.y * Ahn);
        s0 = fmaf(e0, s0, dtv.x * uu0 * B0);
        s1 = fmaf(e1, s1, dtv.y * uu1 * B1);
        T0 += dtv.x;
        T1 += dtv.y;
    }
    lP[0][c][n] = __expf(T0 * Ahn); lS[0][c][n] = s0;
    lP[1][c][n] = __expf(T1 * Ahn); lS[1][c][n] = s1;
    __syncthreads();
    if (tid < 32) {
        int bb = tid >> 4, nn = tid & 15;
        float X = 0.f;
#pragma unroll
        for (int cc = 0; cc < 32; ++cc) {
            lI[bb][cc][nn] = X;
            X = fmaf(lP[bb][cc][nn], X, lS[bb][cc][nn]);
        }
    }
    __syncthreads();

    s0 = lI[0][c][n];
    s1 = lI[1][c][n];
    const float Dh = Dvec[h];
    for (int j = 0; j < 32; ++j) {
        int l = l0 + j;
        float2 dtv = *(const float2*)(sdt + 2 * l);
        u32 uv = *(const u32*)(su + 2 * l);
        float uu0 = __uint_as_float(uv << 16);
        float uu1 = __uint_as_float(uv & 0xffff0000u);
        float2 bc0 = *(const float2*)(proj + (size_t)(2 * l) * 128 + 2 * n);
        float2 bc1 = *(const float2*)(proj + (size_t)(2 * l + 1) * 128 + 2 * n);
        float e0 = __expf(dtv.x * Ahn);
        float e1 = __expf(dtv.y * Ahn);
        s0 = fmaf(e0, s0, dtv.x * uu0 * bc0.x);
        s1 = fmaf(e1, s1, dtv.y * uu1 * bc1.x);
        float v0 = bc0.y * s0;
        float v1 = bc1.y * s1;
        v0 += __shfl_xor(v0, 1, 16);
        v0 += __shfl_xor(v0, 2, 16);
        v0 += __shfl_xor(v0, 4, 16);
        v0 += __shfl_xor(v0, 8, 16);
        v1 += __shfl_xor(v1, 1, 16);
        v1 += __shfl_xor(v1, 2, 16);
        v1 += __shfl_xor(v1, 4, 16);
        v1 += __shfl_xor(v1, 8, 16);
        if (n == 0) {
            yrow[2 * l]     = v0 + uu0 * Dh;
            yrow[2 * l + 1] = v1 + uu1 * Dh;
        }
    }
    __syncthreads();
    {
        int t0 = tid * 4;
        ushort4v rv = *(const ushort4v*)(resT + (size_t)h * 2048 + t0);
        u16 o[4];
#pragma unroll
        for (int i = 0; i < 4; ++i) {
            float r = bf2f(rv[i]);
            float y = yrow[t0 + i];
            o[i] = f2bf(y * (r / (1.f + __expf(-r))));
        }
        *(ulong1*)(zT + (size_t)h * 2048 + t0) = *(ulong1*)o;
    }
}

extern "C" void kernel_launch(void* const* d_in, const int* in_sizes, int n_in,
                              void* d_out, int out_size, void* d_ws, size_t ws_size,
                              hipStream_t stream)
{
    const float* x      = (const float*)d_in[0];
    const float* W_in   = (const float*)d_in[1];
    const float* W_conv = (const float*)d_in[2];
    const float* b_conv = (const float*)d_in[3];
    const float* A_log  = (const float*)d_in[4];
    const float* Dv     = (const float*)d_in[5];
    const float* W_ssm  = (const float*)d_in[6];
    const float* W_dt   = (const float*)d_in[7];
    const float* b_dt   = (const float*)d_in[8];
    const float* W_out  = (const float*)d_in[9];
    float* out = (float*)d_out;

    char* wsc = (char*)d_ws;
    u16*   xb     = (u16*)wsc;
    float* projb  = (float*)wsc;
    u16*   pb_dt  = (u16*)(wsc + (2u << 20));
    u16*   WT_in  = (u16*)(wsc + (4u << 20));
    u16*   u_mh   = (u16*)(wsc + (4u << 20));
    u16*   z_mh   = (u16*)(wsc + (4u << 20));
    u16*   xsbf   = (u16*)(wsc + (12u << 20));
    u16*   zT     = xsbf;
    u16*   resT   = (u16*)(wsc + (20u << 20));
    u16*   WT_cv  = (u16*)(wsc + (28u << 20));
    float* deltaT = (float*)(wsc + (28u << 20));
    u16*   uT     = (u16*)(wsc + (44u << 20));
    u16*   WT_out = (u16*)(wsc + (52u << 20));
    u16*   WT_ssm = (u16*)(wsc + (56u << 20));
    u16*   WT_dt  = (u16*)(wsc + (56u << 20) + (512u << 10));

    dim3 blk(256);

    trans_k<<<dim3(64, 32), blk, 0, stream>>>(W_conv, WT_cv, 4096, 2048);
    trans_k<<<dim3(16, 64), blk, 0, stream>>>(W_in, WT_in, 1024, 4096);
    trans_k<<<dim3(32, 16), blk, 0, stream>>>(W_out, WT_out, 2048, 1024);
    trans_k<<<dim3(32, 2),  blk, 0, stream>>>(W_ssm, WT_ssm, 2048, 96);
    trans_k<<<dim3(1, 32),  blk, 0, stream>>>(W_dt, WT_dt, 64, 2048);
    cvt_k<<<dim3(2048), blk, 0, stream>>>(x, xb);

    gls_k<0><<<dim3(64, 16), blk, 0, stream>>>(
        xb, 1024, WT_in, 1024, nullptr, 0, xsbf, resT, nullptr, 16);

    gls_k<1><<<dim3(32, 16), blk, 0, stream>>>(
        xsbf, 2048, WT_cv, 4096, nullptr, 0, u_mh, uT, b_conv, 64);

    hipMemsetAsync(projb, 0, 2048 * 128 * sizeof(float), stream);
    g3_k<<<dim3(2, 16, 4), blk, 0, stream>>>(u_mh, WT_ssm, projb);

    cvtdt_k<<<dim3(128), blk, 0, stream>>>(projb, pb_dt);

    g4_k<<<dim3(32, 16), blk, 0, stream>>>(pb_dt, WT_dt, b_dt, deltaT);

    scan5_k<<<dim3(2048), dim3(512), 0, stream>>>(
        deltaT, uT, projb, A_log, Dv, resT, zT);

    tbf_k<<<dim3(32, 32), blk, 0, stream>>>(zT, z_mh);

    gls_k<2><<<dim3(16, 16), blk, 0, stream>>>(
        z_mh, 2048, WT_out, 2048, out, 1024, nullptr, nullptr, nullptr, 32);
}